// Round 1
// 960.284 us; speedup vs baseline: 1.1309x; 1.1309x over previous
//
#include <hip/hip_runtime.h>

#define SS 2048

typedef __attribute__((ext_vector_type(4))) float floatx4;
typedef __attribute__((ext_vector_type(8))) __bf16 bf16x8;
typedef __attribute__((ext_vector_type(8))) unsigned short ushortx8;

__device__ inline unsigned short f2bf(float f) {
  union { float f; unsigned u; } x; x.f = f;
  unsigned r = x.u + 0x7fffu + ((x.u >> 16) & 1u);
  return (unsigned short)(r >> 16);
}

// ---------------------------------------------------------------------------
// fp32 -> bf16 (RNE) for query,key,value (4M floats each) and Wq,Wk,Wv,Wo
// (1M each) into one contiguous 16M-ushort workspace region. 4 floats/thread.
// ---------------------------------------------------------------------------
__global__ __launch_bounds__(256) void cvt_bf16(
    const float* __restrict__ q, const float* __restrict__ k,
    const float* __restrict__ v, const float* __restrict__ wq,
    const float* __restrict__ wk, const float* __restrict__ wv,
    const float* __restrict__ wo, unsigned short* __restrict__ dst)
{
  const size_t f = ((size_t)blockIdx.x * 256 + threadIdx.x) * 4;
  const float* src;
  if (f < 4194304) src = q + f;
  else if (f < 8388608) src = k + (f - 4194304);
  else if (f < 12582912) src = v + (f - 8388608);
  else {
    size_t off = f - 12582912;
    unsigned wi = (unsigned)(off >> 20);
    const float* wp = wi == 0 ? wq : wi == 1 ? wk : wi == 2 ? wv : wo;
    src = wp + (off & 1048575);
  }
  float4 x = *(const float4*)src;
  *(ushort4*)&dst[f] = make_ushort4(f2bf(x.x), f2bf(x.y), f2bf(x.z), f2bf(x.w));
}

// ---------------------------------------------------------------------------
// GEMM core: out[m][n] = X[m][:] . W[n][:] + bias[n], X/W bf16 [*][1024].
// Tile 128x128, BK=64, 4 waves (2x2), 32 MFMA per k-step. mode 0: bf16
// [b,h,s,dh]; mode 1: bf16 [b,h,dh,s]; mode 2: fp32 [m][n].
// LDS stride 72 ushorts = 144B: b128 frag reads tile all 32 banks.
// ---------------------------------------------------------------------------
__device__ __forceinline__ void gemm_body(
    const unsigned short* __restrict__ X, const unsigned short* __restrict__ W,
    const float* __restrict__ bias, void* __restrict__ outp, int mode)
{
  __shared__ unsigned short lA[128][72];
  __shared__ unsigned short lB[128][72];
  const int t = threadIdx.x;
  const int nb = blockIdx.x, mb = blockIdx.y;
  const int lane = t & 63, w = t >> 6;
  const int lr = lane & 15, lq = lane >> 4;
  const int wm = w >> 1, wn = w & 1;

  floatx4 acc[4][4];
  for (int j = 0; j < 4; ++j) {
    float bj = bias[nb * 128 + wn * 64 + j * 16 + lr];
    floatx4 bj4 = {bj, bj, bj, bj};
    for (int i = 0; i < 4; ++i) acc[i][j] = bj4;
  }

  for (int kc = 0; kc < 16; ++kc) {
    for (int i = 0; i < 4; ++i) {
      int idx = t + i * 256;            // 0..1023: 128 rows x 8 chunks of 16B
      int row = idx >> 3, c = idx & 7;
      *(uint4*)&lA[row][c * 8] =
          *(const uint4*)&X[(size_t)(mb * 128 + row) * 1024 + kc * 64 + c * 8];
      *(uint4*)&lB[row][c * 8] =
          *(const uint4*)&W[(size_t)(nb * 128 + row) * 1024 + kc * 64 + c * 8];
    }
    __syncthreads();
    for (int kk = 0; kk < 2; ++kk) {
      bf16x8 aF[4], bF[4];
      for (int i = 0; i < 4; ++i)
        aF[i] = *(const bf16x8*)&lA[wm * 64 + i * 16 + lr][kk * 32 + lq * 8];
      for (int j = 0; j < 4; ++j)
        bF[j] = *(const bf16x8*)&lB[wn * 64 + j * 16 + lr][kk * 32 + lq * 8];
      for (int i = 0; i < 4; ++i)
        for (int j = 0; j < 4; ++j)
          acc[i][j] = __builtin_amdgcn_mfma_f32_16x16x32_bf16(aF[i], bF[j], acc[i][j], 0, 0, 0);
    }
    __syncthreads();
  }

  if (mode == 2) {
    float* O = (float*)outp;
    for (int i = 0; i < 4; ++i) {
      int m0 = mb * 128 + wm * 64 + i * 16 + lq * 4;
      for (int j = 0; j < 4; ++j) {
        int n = nb * 128 + wn * 64 + j * 16 + lr;
        for (int r = 0; r < 4; ++r)
          O[(size_t)(m0 + r) * 1024 + n] = acc[i][j][r];
      }
    }
  } else if (mode == 0) {
    unsigned short* O = (unsigned short*)outp;
    for (int i = 0; i < 4; ++i) {
      int m0 = mb * 128 + wm * 64 + i * 16 + lq * 4;
      for (int j = 0; j < 4; ++j) {
        int n = nb * 128 + wn * 64 + j * 16 + lr;
        int h = n >> 6, dh = n & 63;
        for (int r = 0; r < 4; ++r) {
          int m = m0 + r;
          int b = m >> 11, s = m & 2047;
          O[((size_t)(b * 16 + h) * 2048 + s) * 64 + dh] = f2bf(acc[i][j][r]);
        }
      }
    }
  } else {  // mode 1: [b][h][dh][s]
    unsigned short* O = (unsigned short*)outp;
    for (int i = 0; i < 4; ++i) {
      int m0 = mb * 128 + wm * 64 + i * 16 + lq * 4;
      int b = m0 >> 11, s0 = m0 & 2047;
      for (int j = 0; j < 4; ++j) {
        int n = nb * 128 + wn * 64 + j * 16 + lr;
        int h = n >> 6, dh = n & 63;
        *(ushort4*)&O[((size_t)(b * 16 + h) * 64 + dh) * 2048 + s0] =
            make_ushort4(f2bf(acc[i][j][0]), f2bf(acc[i][j][1]),
                         f2bf(acc[i][j][2]), f2bf(acc[i][j][3]));
      }
    }
  }
}

// Fused QKV projection: blockIdx.z selects input/weight/output. 768 blocks
// = 3 blocks/CU = 12 waves/CU (was 1 wave/SIMD per separate launch).
__global__ __launch_bounds__(256) void gemm_qkv(
    const unsigned short* __restrict__ base, const float* __restrict__ bq,
    const float* __restrict__ bk, const float* __restrict__ bv,
    unsigned short* __restrict__ q_s, unsigned short* __restrict__ k_s,
    unsigned short* __restrict__ v_t)
{
  const int z = blockIdx.z;
  const unsigned short* X = base + (size_t)z * 4194304;
  const unsigned short* W = base + 12582912 + (size_t)z * 1048576;
  const float* bias = z == 0 ? bq : z == 1 ? bk : bv;
  void* out = z == 0 ? (void*)q_s : z == 1 ? (void*)k_s : (void*)v_t;
  gemm_body(X, W, bias, out, z == 2 ? 1 : 0);
}

__global__ __launch_bounds__(256) void gemm_out(
    const unsigned short* __restrict__ ctxb, const unsigned short* __restrict__ Wob,
    const float* __restrict__ bo, float* __restrict__ out)
{
  gemm_body(ctxb, Wob, bo, (void*)out, 2);
}

// ---------------------------------------------------------------------------
// Attention: one wave per 16 query rows (4096 waves = 16 waves/CU, 2x the
// old occupancy). XCD-chunked swizzle: blocks with bid%8==x get contiguous
// vb -> 4 bh per XCD, K+V (2MB) L2-resident. Pass A: row sums of exp(s/8).
// Pass B: recompute, stage p fp32 in per-wave LDS, store probs as coalesced
// float4 (256B/row), convert to bf16 frags on LDS read for PV MFMA.
// Writes ctx as bf16 (identical to the f2bf the old final GEMM applied).
// ---------------------------------------------------------------------------
__global__ __launch_bounds__(256) void attn_kernel(
    const unsigned short* __restrict__ Q, const unsigned short* __restrict__ K,
    const unsigned short* __restrict__ Vt, float* __restrict__ attn,
    unsigned short* __restrict__ ctxb)
{
  __shared__ float pf[4][16][68];   // per-wave p tile, stride 68 (16B-aligned)
  const int t = threadIdx.x;
  const int w = t >> 6, lane = t & 63;
  const int lr = lane & 15, lq = lane >> 4;
  const int bid = blockIdx.x;
  const int vb = ((bid & 7) << 7) | (bid >> 3);  // XCD chunking (1024 % 8 == 0)
  const int gw = vb * 4 + w;           // 0..4095
  const int bh = gw >> 7;              // 0..31 (128 chunks per bh)
  const int q0 = (gw & 127) * 16;      // query row base
  const int b = bh >> 4, h = bh & 15;

  const unsigned short* qp = Q + (size_t)bh * SS * 64;
  const unsigned short* kp = K + (size_t)bh * SS * 64;
  const unsigned short* vp = Vt + (size_t)bh * 64 * SS;
  float* aout = attn + (size_t)bh * SS * SS;

  bf16x8 qF[2];
  for (int kk = 0; kk < 2; ++kk)
    qF[kk] = *(const bf16x8*)&qp[(size_t)(q0 + lr) * 64 + kk * 32 + lq * 8];

  const floatx4 zf = {0.f, 0.f, 0.f, 0.f};
  float lsum[4] = {0.f, 0.f, 0.f, 0.f};

  // ---- pass A: row sums of exp(s * 0.125) ----
  for (int kc = 0; kc < 32; ++kc) {
    for (int nt = 0; nt < 4; ++nt) {
      const size_t kbase = (size_t)(kc * 64 + nt * 16 + lr) * 64 + lq * 8;
      bf16x8 kF0 = *(const bf16x8*)&kp[kbase];
      bf16x8 kF1 = *(const bf16x8*)&kp[kbase + 32];
      floatx4 s = __builtin_amdgcn_mfma_f32_16x16x32_bf16(qF[0], kF0, zf, 0, 0, 0);
      s = __builtin_amdgcn_mfma_f32_16x16x32_bf16(qF[1], kF1, s, 0, 0, 0);
      for (int r = 0; r < 4; ++r)
        lsum[r] += __expf(s[r] * 0.125f);
    }
  }
  float rl[4];
  for (int r = 0; r < 4; ++r) {
    float v = lsum[r];
    v += __shfl_xor(v, 1);
    v += __shfl_xor(v, 2);
    v += __shfl_xor(v, 4);
    v += __shfl_xor(v, 8);
    rl[r] = 1.0f / v;
  }

  floatx4 oF[4];
  for (int nt = 0; nt < 4; ++nt) oF[nt] = zf;

  // ---- pass B: recompute, write probs, accumulate ctx ----
  for (int kc = 0; kc < 32; ++kc) {
    for (int nt = 0; nt < 4; ++nt) {
      const size_t kbase = (size_t)(kc * 64 + nt * 16 + lr) * 64 + lq * 8;
      bf16x8 kF0 = *(const bf16x8*)&kp[kbase];
      bf16x8 kF1 = *(const bf16x8*)&kp[kbase + 32];
      floatx4 s = __builtin_amdgcn_mfma_f32_16x16x32_bf16(qF[0], kF0, zf, 0, 0, 0);
      s = __builtin_amdgcn_mfma_f32_16x16x32_bf16(qF[1], kF1, s, 0, 0, 0);
      for (int r = 0; r < 4; ++r)
        pf[w][lq * 4 + r][nt * 16 + lr] = __expf(s[r] * 0.125f) * rl[r];
    }
    // coalesced prob stores: 16 lanes x float4 = one full 256B row per instr
    {
      const int sc = lane & 15, sr = lane >> 4;
      for (int i = 0; i < 4; ++i) {
        float4 v4 = *(const float4*)&pf[w][sr + i * 4][sc * 4];
        *(float4*)&aout[(size_t)(q0 + sr + i * 4) * 2048 + kc * 64 + sc * 4] = v4;
      }
    }
    for (int kk = 0; kk < 2; ++kk) {
      const float* pr = &pf[w][lr][kk * 32 + lq * 8];
      float4 p0 = *(const float4*)pr;
      float4 p1 = *(const float4*)(pr + 4);
      union { ushortx8 u; bf16x8 b; } ap;
      ap.u[0] = f2bf(p0.x); ap.u[1] = f2bf(p0.y);
      ap.u[2] = f2bf(p0.z); ap.u[3] = f2bf(p0.w);
      ap.u[4] = f2bf(p1.x); ap.u[5] = f2bf(p1.y);
      ap.u[6] = f2bf(p1.z); ap.u[7] = f2bf(p1.w);
      for (int nt = 0; nt < 4; ++nt) {
        bf16x8 vF = *(const bf16x8*)&vp[(size_t)(nt * 16 + lr) * 2048 + kc * 64 + kk * 32 + lq * 8];
        oF[nt] = __builtin_amdgcn_mfma_f32_16x16x32_bf16(ap.b, vF, oF[nt], 0, 0, 0);
      }
    }
  }

  // ctx bf16 [b*2048+row][h*64+dh]
  for (int nt = 0; nt < 4; ++nt)
    for (int r = 0; r < 4; ++r) {
      int row = q0 + lq * 4 + r;
      int col = h * 64 + nt * 16 + lr;
      ctxb[(size_t)(b * 2048 + row) * 1024 + col] = f2bf(oF[nt][r]);
    }
}

extern "C" void kernel_launch(void* const* d_in, const int* in_sizes, int n_in,
                              void* d_out, int out_size, void* d_ws, size_t ws_size,
                              hipStream_t stream) {
  (void)in_sizes; (void)n_in; (void)out_size; (void)ws_size;
  const float* query = (const float*)d_in[0];
  const float* key   = (const float*)d_in[1];
  const float* value = (const float*)d_in[2];
  const float* Wq = (const float*)d_in[3];
  const float* bq = (const float*)d_in[4];
  const float* Wk = (const float*)d_in[5];
  const float* bk = (const float*)d_in[6];
  const float* Wv = (const float*)d_in[7];
  const float* bv = (const float*)d_in[8];
  const float* Wo = (const float*)d_in[9];
  const float* bo = (const float*)d_in[10];
  float* outF = (float*)d_out;

  // workspace (64 MB): [0,16M) bf16 of {q,k,v,Wq,Wk,Wv,Wo}; then q_s, k_s
  // (bf16 [b,h,s,dh]); v_t (bf16 [b,h,dh,s]); ctxb (bf16 [m][n]).
  unsigned short* cw  = (unsigned short*)d_ws;
  unsigned short* q_s = cw + 16777216;
  unsigned short* k_s = q_s + 4194304;
  unsigned short* v_t = k_s + 4194304;
  unsigned short* ctxb = v_t + 4194304;

  cvt_bf16<<<dim3(16384), dim3(256), 0, stream>>>(query, key, value, Wq, Wk, Wv, Wo, cw);
  gemm_qkv<<<dim3(8, 32, 3), dim3(256), 0, stream>>>(cw, bq, bk, bv, q_s, k_s, v_t);
  attn_kernel<<<dim3(1024), dim3(256), 0, stream>>>(q_s, k_s, v_t, outF + 4194304, ctxb);
  gemm_out<<<dim3(8, 32), dim3(256), 0, stream>>>(ctxb, cw + 15728640, bo, outF);
}

// Round 3
// 948.825 us; speedup vs baseline: 1.1445x; 1.0121x over previous
//
#include <hip/hip_runtime.h>

#define SS 2048

typedef __attribute__((ext_vector_type(4))) float floatx4;
typedef __attribute__((ext_vector_type(8))) __bf16 bf16x8;
typedef __attribute__((ext_vector_type(8))) unsigned short ushortx8;

__device__ inline unsigned short f2bf(float f) {
  union { float f; unsigned u; } x; x.f = f;
  unsigned r = x.u + 0x7fffu + ((x.u >> 16) & 1u);
  return (unsigned short)(r >> 16);
}

// global -> LDS direct DMA, 16B per lane (m97 structure: dest must be
// wave-uniform base + lane*16; our staging index is exactly that).
__device__ __forceinline__ void gload_lds16(const void* g, void* l) {
  __builtin_amdgcn_global_load_lds(
      (const __attribute__((address_space(1))) unsigned int*)g,
      (__attribute__((address_space(3))) unsigned int*)l, 16, 0, 0);
}

// ---------------------------------------------------------------------------
// fp32 -> bf16 (RNE) for query,key,value (4M floats each) and Wq,Wk,Wv,Wo
// (1M each) into one contiguous 16M-ushort workspace region.
// ---------------------------------------------------------------------------
__global__ __launch_bounds__(256) void cvt_bf16(
    const float* __restrict__ q, const float* __restrict__ k,
    const float* __restrict__ v, const float* __restrict__ wq,
    const float* __restrict__ wk, const float* __restrict__ wv,
    const float* __restrict__ wo, unsigned short* __restrict__ dst)
{
  const size_t f = ((size_t)blockIdx.x * 256 + threadIdx.x) * 4;
  const float* src;
  if (f < 4194304) src = q + f;
  else if (f < 8388608) src = k + (f - 4194304);
  else if (f < 12582912) src = v + (f - 8388608);
  else {
    size_t off = f - 12582912;
    unsigned wi = (unsigned)(off >> 20);
    const float* wp = wi == 0 ? wq : wi == 1 ? wk : wi == 2 ? wv : wo;
    src = wp + (off & 1048575);
  }
  float4 x = *(const float4*)src;
  *(ushort4*)&dst[f] = make_ushort4(f2bf(x.x), f2bf(x.y), f2bf(x.z), f2bf(x.w));
}

// ---------------------------------------------------------------------------
// GEMM core (m97 structure): out[m][n] = X[m][:].W[n][:] + bias[n], bf16 in.
// BK=32, global_load_lds width-16 staging, 2-barrier k-loop, linear LDS.
// BMxBN tile, 4 waves (2x2). MODE 0: bf16 [b,h,s,dh]; 1: bf16 [b,h,dh,s];
// 2: fp32 [m][n].
// ---------------------------------------------------------------------------
template<int BM, int BN, int MODE>
__device__ __forceinline__ void gemm_core(
    unsigned short* lds,
    const unsigned short* __restrict__ X, const unsigned short* __restrict__ W,
    const float* __restrict__ bias, void* __restrict__ outp)
{
  constexpr int MF = BM / 32, NF = BN / 32;
  constexpr int C = (BM + BN) / 64;           // 4KB staging chunks per k-step
  unsigned short* lA = lds;                    // [BM][32] bf16, linear 64B rows
  unsigned short* lB = lds + BM * 32;          // [BN][32]
  const int t = threadIdx.x;
  const int nb = blockIdx.x, mb = blockIdx.y;
  const int lane = t & 63, w = t >> 6;
  const int lr = lane & 15, lq = lane >> 4;
  const int wm = w >> 1, wn = w & 1;

  floatx4 acc[MF][NF];
  for (int j = 0; j < NF; ++j) {
    float bj = bias[nb * BN + wn * (BN / 2) + j * 16 + lr];
    floatx4 b4 = {bj, bj, bj, bj};
    for (int i = 0; i < MF; ++i) acc[i][j] = b4;
  }

  for (int kc = 0; kc < 32; ++kc) {
    for (int c = 0; c < C; ++c) {
      const int idx = c * 256 + t;            // 16B units; wave-contig dest
      const unsigned short* src;
      if (c * 256 < BM * 4) {                 // A region (chunk-aligned)
        const int row = idx >> 2, col = idx & 3;
        src = &X[(size_t)(mb * BM + row) * 1024 + kc * 32 + col * 8];
      } else {
        const int i2 = idx - BM * 4;
        const int row = i2 >> 2, col = i2 & 3;
        src = &W[(size_t)(nb * BN + row) * 1024 + kc * 32 + col * 8];
      }
      gload_lds16(src, &lds[(size_t)idx * 8]);
    }
    __syncthreads();                           // drains vmcnt
    bf16x8 aF[MF], bF[NF];
    for (int i = 0; i < MF; ++i)
      aF[i] = *(const bf16x8*)&lA[(wm * (BM / 2) + i * 16 + lr) * 32 + lq * 8];
    for (int j = 0; j < NF; ++j)
      bF[j] = *(const bf16x8*)&lB[(wn * (BN / 2) + j * 16 + lr) * 32 + lq * 8];
    for (int i = 0; i < MF; ++i)
      for (int j = 0; j < NF; ++j)
        acc[i][j] = __builtin_amdgcn_mfma_f32_16x16x32_bf16(aF[i], bF[j], acc[i][j], 0, 0, 0);
    __syncthreads();
  }

  if (MODE == 2) {
    float* O = (float*)outp;
    for (int i = 0; i < MF; ++i) {
      int m0 = mb * BM + wm * (BM / 2) + i * 16 + lq * 4;
      for (int j = 0; j < NF; ++j) {
        int n = nb * BN + wn * (BN / 2) + j * 16 + lr;
        for (int r = 0; r < 4; ++r)
          O[(size_t)(m0 + r) * 1024 + n] = acc[i][j][r];
      }
    }
  } else if (MODE == 0) {
    unsigned short* O = (unsigned short*)outp;
    for (int i = 0; i < MF; ++i) {
      int m0 = mb * BM + wm * (BM / 2) + i * 16 + lq * 4;
      for (int j = 0; j < NF; ++j) {
        int n = nb * BN + wn * (BN / 2) + j * 16 + lr;
        int h = n >> 6, dh = n & 63;
        for (int r = 0; r < 4; ++r) {
          int m = m0 + r;
          int b = m >> 11, s = m & 2047;
          O[((size_t)(b * 16 + h) * 2048 + s) * 64 + dh] = f2bf(acc[i][j][r]);
        }
      }
    }
  } else {  // MODE 1: [b][h][dh][s]
    unsigned short* O = (unsigned short*)outp;
    for (int i = 0; i < MF; ++i) {
      int m0 = mb * BM + wm * (BM / 2) + i * 16 + lq * 4;
      int b = m0 >> 11, s0 = m0 & 2047;
      for (int j = 0; j < NF; ++j) {
        int n = nb * BN + wn * (BN / 2) + j * 16 + lr;
        int h = n >> 6, dh = n & 63;
        *(ushort4*)&O[((size_t)(b * 16 + h) * 64 + dh) * 2048 + s0] =
            make_ushort4(f2bf(acc[i][j][0]), f2bf(acc[i][j][1]),
                         f2bf(acc[i][j][2]), f2bf(acc[i][j][3]));
      }
    }
  }
}

// Fused QKV projection: 768 blocks = 3/CU.
__global__ __launch_bounds__(256) void gemm_qkv(
    const unsigned short* __restrict__ base, const float* __restrict__ bq,
    const float* __restrict__ bk, const float* __restrict__ bv,
    unsigned short* __restrict__ q_s, unsigned short* __restrict__ k_s,
    unsigned short* __restrict__ v_t)
{
  __shared__ unsigned short lds[(128 + 128) * 32];
  const int z = blockIdx.z;
  const unsigned short* X = base + (size_t)z * 4194304;
  const unsigned short* W = base + 12582912 + (size_t)z * 1048576;
  if (z == 0)      gemm_core<128, 128, 0>(lds, X, W, bq, q_s);
  else if (z == 1) gemm_core<128, 128, 0>(lds, X, W, bk, k_s);
  else             gemm_core<128, 128, 1>(lds, X, W, bv, v_t);
}

// Output projection: 128x64 tile -> 512 blocks = 2/CU (was 1/CU starved).
__global__ __launch_bounds__(256) void gemm_out_k(
    const unsigned short* __restrict__ ctxb, const unsigned short* __restrict__ Wob,
    const float* __restrict__ bo, float* __restrict__ out)
{
  __shared__ unsigned short lds[(128 + 64) * 32];
  gemm_core<128, 64, 2>(lds, ctxb, Wob, bo, out);
}

// ---------------------------------------------------------------------------
// Attention: one wave per 16 query rows. __launch_bounds__(256,3) lifts the
// VGPR cap to ~170 so the k-chunk fragment loads can ALL stay in flight
// (round-1's 52-VGPR schedule serialized them: load->wait->mfma per pair).
// Explicit software pipeline: K double-buffered (kA/kB, kc unrolled by 2),
// V issued at chunk start and consumed at chunk end.
// ---------------------------------------------------------------------------
__global__ __launch_bounds__(256, 3) void attn_kernel(
    const unsigned short* __restrict__ Q, const unsigned short* __restrict__ K,
    const unsigned short* __restrict__ Vt, float* __restrict__ attn,
    unsigned short* __restrict__ ctxb)
{
  __shared__ float pf[4][16][68];   // per-wave p tile
  const int t = threadIdx.x;
  const int w = t >> 6, lane = t & 63;
  const int lr = lane & 15, lq = lane >> 4;
  const int bid = blockIdx.x;
  const int vb = ((bid & 7) << 7) | (bid >> 3);  // XCD chunking
  const int gw = vb * 4 + w;           // 0..4095
  const int bh = gw >> 7;              // 0..31
  const int q0 = (gw & 127) * 16;      // query row base
  const int b = bh >> 4, h = bh & 15;

  const unsigned short* qp = Q + (size_t)bh * SS * 64;
  const unsigned short* kp = K + (size_t)bh * SS * 64;
  const unsigned short* vp = Vt + (size_t)bh * 64 * SS;
  float* aout = attn + (size_t)bh * SS * SS;

  bf16x8 qF0 = *(const bf16x8*)&qp[(size_t)(q0 + lr) * 64 + lq * 8];
  bf16x8 qF1 = *(const bf16x8*)&qp[(size_t)(q0 + lr) * 64 + 32 + lq * 8];

  const floatx4 zf = {0.f, 0.f, 0.f, 0.f};

#define LOADK(KC, arr) do { \
    const unsigned short* kb0 = kp + (size_t)((KC) * 64 + lr) * 64 + lq * 8; \
    arr[0] = *(const bf16x8*)kb0;              arr[1] = *(const bf16x8*)(kb0 + 32); \
    arr[2] = *(const bf16x8*)(kb0 + 1024);     arr[3] = *(const bf16x8*)(kb0 + 1024 + 32); \
    arr[4] = *(const bf16x8*)(kb0 + 2048);     arr[5] = *(const bf16x8*)(kb0 + 2048 + 32); \
    arr[6] = *(const bf16x8*)(kb0 + 3072);     arr[7] = *(const bf16x8*)(kb0 + 3072 + 32); \
  } while (0)

#define LOADV(KC, arr) do { \
    const unsigned short* vb0 = vp + (size_t)lr * 2048 + (KC) * 64 + lq * 8; \
    arr[0] = *(const bf16x8*)vb0;               arr[4] = *(const bf16x8*)(vb0 + 32); \
    arr[1] = *(const bf16x8*)(vb0 + 16 * 2048); arr[5] = *(const bf16x8*)(vb0 + 16 * 2048 + 32); \
    arr[2] = *(const bf16x8*)(vb0 + 32 * 2048); arr[6] = *(const bf16x8*)(vb0 + 32 * 2048 + 32); \
    arr[3] = *(const bf16x8*)(vb0 + 48 * 2048); arr[7] = *(const bf16x8*)(vb0 + 48 * 2048 + 32); \
  } while (0)

#define QKSUM(arr) do { \
    for (int nt = 0; nt < 4; ++nt) { \
      floatx4 s = __builtin_amdgcn_mfma_f32_16x16x32_bf16(qF0, arr[nt * 2], zf, 0, 0, 0); \
      s = __builtin_amdgcn_mfma_f32_16x16x32_bf16(qF1, arr[nt * 2 + 1], s, 0, 0, 0); \
      for (int r = 0; r < 4; ++r) lsum[r] += __expf(s[r] * 0.125f); \
    } \
  } while (0)

  bf16x8 kA[8], kB[8];
  float lsum[4] = {0.f, 0.f, 0.f, 0.f};

  // ---- pass A: row sums of exp(s * 0.125), K double-buffered ----
  LOADK(0, kA);
  for (int kc = 0; kc < 32; kc += 2) {
    LOADK(kc + 1, kB);
    QKSUM(kA);
    if (kc + 2 < 32) LOADK(kc + 2, kA);
    QKSUM(kB);
  }
  float rl[4];
  for (int r = 0; r < 4; ++r) {
    float v = lsum[r];
    v += __shfl_xor(v, 1);
    v += __shfl_xor(v, 2);
    v += __shfl_xor(v, 4);
    v += __shfl_xor(v, 8);
    rl[r] = 1.0f / v;
  }

  floatx4 oF[4];
  for (int nt = 0; nt < 4; ++nt) oF[nt] = zf;
  bf16x8 vR[8];

  // per chunk: issue V early; QK+exp; issue next K; prob stores; PV.
#define PB(KC, KCUR, KNEXT, GUARD) do { \
    LOADV(KC, vR); \
    for (int nt = 0; nt < 4; ++nt) { \
      floatx4 s = __builtin_amdgcn_mfma_f32_16x16x32_bf16(qF0, KCUR[nt * 2], zf, 0, 0, 0); \
      s = __builtin_amdgcn_mfma_f32_16x16x32_bf16(qF1, KCUR[nt * 2 + 1], s, 0, 0, 0); \
      for (int r = 0; r < 4; ++r) \
        pf[w][lq * 4 + r][nt * 16 + lr] = __expf(s[r] * 0.125f) * rl[r]; \
    } \
    if (GUARD) LOADK((KC) + 1, KNEXT); \
    { const int sc = lane & 15, sr = lane >> 4; \
      for (int i = 0; i < 4; ++i) { \
        float4 v4 = *(const float4*)&pf[w][sr + i * 4][sc * 4]; \
        *(float4*)&aout[(size_t)(q0 + sr + i * 4) * 2048 + (KC) * 64 + sc * 4] = v4; } } \
    for (int kk = 0; kk < 2; ++kk) { \
      const float* pr = &pf[w][lr][kk * 32 + lq * 8]; \
      float4 p0 = *(const float4*)pr; \
      float4 p1 = *(const float4*)(pr + 4); \
      union { ushortx8 u; bf16x8 bb; } ap; \
      ap.u[0] = f2bf(p0.x); ap.u[1] = f2bf(p0.y); ap.u[2] = f2bf(p0.z); ap.u[3] = f2bf(p0.w); \
      ap.u[4] = f2bf(p1.x); ap.u[5] = f2bf(p1.y); ap.u[6] = f2bf(p1.z); ap.u[7] = f2bf(p1.w); \
      for (int nt2 = 0; nt2 < 4; ++nt2) \
        oF[nt2] = __builtin_amdgcn_mfma_f32_16x16x32_bf16(ap.bb, vR[kk * 4 + nt2], oF[nt2], 0, 0, 0); \
    } \
  } while (0)

  // ---- pass B ----
  LOADK(0, kA);
  for (int kc = 0; kc < 32; kc += 2) {
    PB(kc, kA, kB, 1);
    PB(kc + 1, kB, kA, (kc + 2) < 32);
  }

#undef LOADK
#undef LOADV
#undef QKSUM
#undef PB

  // ctx bf16 [b*2048+row][h*64+dh]
  for (int nt = 0; nt < 4; ++nt)
    for (int r = 0; r < 4; ++r) {
      int row = q0 + lq * 4 + r;
      int col = h * 64 + nt * 16 + lr;
      ctxb[(size_t)(b * 2048 + row) * 1024 + col] = f2bf(oF[nt][r]);
    }
}

extern "C" void kernel_launch(void* const* d_in, const int* in_sizes, int n_in,
                              void* d_out, int out_size, void* d_ws, size_t ws_size,
                              hipStream_t stream) {
  (void)in_sizes; (void)n_in; (void)out_size; (void)ws_size;
  const float* query = (const float*)d_in[0];
  const float* key   = (const float*)d_in[1];
  const float* value = (const float*)d_in[2];
  const float* Wq = (const float*)d_in[3];
  const float* bq = (const float*)d_in[4];
  const float* Wk = (const float*)d_in[5];
  const float* bk = (const float*)d_in[6];
  const float* Wv = (const float*)d_in[7];
  const float* bv = (const float*)d_in[8];
  const float* Wo = (const float*)d_in[9];
  const float* bo = (const float*)d_in[10];
  float* outF = (float*)d_out;

  // workspace: [0,16M) bf16 {q,k,v,Wq,Wk,Wv,Wo}; q_s, k_s [b,h,s,dh];
  // v_t [b,h,dh,s]; ctxb bf16 [m][n].
  unsigned short* cw  = (unsigned short*)d_ws;
  unsigned short* q_s = cw + 16777216;
  unsigned short* k_s = q_s + 4194304;
  unsigned short* v_t = k_s + 4194304;
  unsigned short* ctxb = v_t + 4194304;

  cvt_bf16<<<dim3(16384), dim3(256), 0, stream>>>(query, key, value, Wq, Wk, Wv, Wo, cw);
  gemm_qkv<<<dim3(8, 32, 3), dim3(256), 0, stream>>>(cw, bq, bk, bv, q_s, k_s, v_t);
  attn_kernel<<<dim3(1024), dim3(256), 0, stream>>>(q_s, k_s, v_t, outF + 4194304, ctxb);
  gemm_out_k<<<dim3(16, 32), dim3(256), 0, stream>>>(ctxb, cw + 15728640, bo, outF);
}